// Round 1
// baseline (622.022 us; speedup 1.0000x reference)
//
#include <hip/hip_runtime.h>

#define HH 256
#define WW 256
#define HW (HH * WW)

// Pre-kernel: E[i,m,l] = exp(w[i,m,l]), 120 values into workspace.
__global__ void exp_kernel(const float* __restrict__ w, float* __restrict__ E) {
    int t = threadIdx.x;
    if (t < 120) E[t] = expf(w[t]);
}

__device__ __forceinline__ float sgnf(float d) {
    return (d > 0.0f) ? 1.0f : ((d < 0.0f) ? -1.0f : 0.0f);
}

// One block per (n, row). 256 threads = one row of pixels.
// Each thread computes all 67 output channels for its pixel.
__global__ __launch_bounds__(256) void lbp_kernel(
    const float* __restrict__ x,    // (32,3,256,256)
    const float* __restrict__ E,    // exp(w), (3,5,8) flat
    const float* __restrict__ wl,   // (5,64) flat
    float* __restrict__ out)        // (32,67,256,256)
{
    const int tid = threadIdx.x;
    const int bid = blockIdx.x;
    const int n = bid >> 8;
    const int r = bid & 255;
    const int c = tid;

    float* ob = out + (size_t)n * 67 * HW + (size_t)r * WW + c;

    // Border: zero-pad (harness poisons d_out with 0xAA).
    if (r == 0 || r == HH - 1 || c == 0 || c == WW - 1) {
        #pragma unroll
        for (int ch = 0; ch < 67; ++ch) ob[(size_t)ch * HW] = 0.0f;
        return;
    }

    const float* xb = x + (size_t)n * 3 * HW + (size_t)r * WW + c;

    float t[5] = {0.f, 0.f, 0.f, 0.f, 0.f};

    #pragma unroll
    for (int i = 0; i < 3; ++i) {
        const float* xp = xb + i * HW;
        const float ctr = xp[0];
        ob[i * HW] = ctr;  // channels 0..2 = center copy

        float s[8];
        // _OFFSETS order: (-1,-1),(-1,0),(-1,+1),(0,-1),(+1,-1),(+1,0),(+1,+1),(0,+1)
        s[0] = sgnf(ctr - xp[-WW - 1]);
        s[1] = sgnf(ctr - xp[-WW    ]);
        s[2] = sgnf(ctr - xp[-WW + 1]);
        s[3] = sgnf(ctr - xp[-1]);
        s[4] = sgnf(ctr - xp[ WW - 1]);
        s[5] = sgnf(ctr - xp[ WW    ]);
        s[6] = sgnf(ctr - xp[ WW + 1]);
        s[7] = sgnf(ctr - xp[ 1]);

        // t[m] += sum_l s[l] * E[i,m,l] — E uniform-indexed -> s_load/SGPR
        #pragma unroll
        for (int m = 0; m < 5; ++m) {
            float acc = t[m];
            #pragma unroll
            for (int l = 0; l < 8; ++l)
                acc = fmaf(s[l], E[i * 40 + m * 8 + l], acc);
            t[m] = acc;
        }
    }

    // out[o] = sum_m t[m] * wl[m,o] — wl uniform-indexed -> SGPR
    #pragma unroll
    for (int o = 0; o < 64; ++o) {
        float v = t[0] * wl[o];
        #pragma unroll
        for (int m = 1; m < 5; ++m)
            v = fmaf(t[m], wl[m * 64 + o], v);
        ob[(size_t)(3 + o) * HW] = v;
    }
}

extern "C" void kernel_launch(void* const* d_in, const int* in_sizes, int n_in,
                              void* d_out, int out_size, void* d_ws, size_t ws_size,
                              hipStream_t stream) {
    const float* x  = (const float*)d_in[0];
    const float* w  = (const float*)d_in[1];
    const float* wl = (const float*)d_in[2];
    float* out = (float*)d_out;
    float* E   = (float*)d_ws;   // 120 floats

    exp_kernel<<<1, 128, 0, stream>>>(w, E);
    lbp_kernel<<<32 * 256, 256, 0, stream>>>(x, E, wl, out);
}

// Round 3
// 570.043 us; speedup vs baseline: 1.0912x; 1.0912x over previous
//
#include <hip/hip_runtime.h>

#define HH 256
#define WW 256
#define HW (HH * WW)

// Prep: E[i,m,l] = exp(w[i,m,l]) (120 floats) at ws[0..119];
//       wlT[o,m] = wl[m,o]       (320 floats) at ws[128..447].
__global__ void prep_kernel(const float* __restrict__ w, const float* __restrict__ wl,
                            float* __restrict__ ws) {
    int t = threadIdx.x;
    if (t < 120) ws[t] = expf(w[t]);
    if (t >= 128 && t < 128 + 320) {
        int idx = t - 128;          // idx = o*5 + m
        int o = idx / 5, m = idx - o * 5;
        ws[t] = wl[m * 64 + o];
    }
}

__device__ __forceinline__ float sgnf(float d) {
    return (d > 0.0f) ? 1.0f : ((d < 0.0f) ? -1.0f : 0.0f);
}

// Grid: 32 images x 64 row-quads, 256 threads.
// Wave w (0..3) owns row q*4+w; lane owns a 4-column quad. All stores dwordx4.
__global__ __launch_bounds__(256) void lbp_kernel(
    const float* __restrict__ x,    // (32,3,256,256)
    const float* __restrict__ ws,   // E[120] @0, wlT[320] @128
    float* __restrict__ out)        // (32,67,256,256)
{
    const int tid  = threadIdx.x;
    const int bid  = blockIdx.x;
    const int n    = bid >> 6;
    const int q    = bid & 63;
    const int wv   = tid >> 6;
    const int lane = tid & 63;
    const int r    = q * 4 + wv;
    const int cb   = lane * 4;

    float* ob = out + (size_t)n * 67 * HW + (size_t)r * WW + cb;

    // Rows 0 / 255: wave-uniform zero fill (output is poisoned 0xAA).
    if (r == 0 || r == HH - 1) {
        const float4 z = {0.f, 0.f, 0.f, 0.f};
        #pragma unroll
        for (int ch = 0; ch < 67; ++ch)
            *(float4*)(ob + (size_t)ch * HW) = z;
        return;
    }

    // Clamped scalar-neighbor columns (keeps all loads in-bounds; border
    // pixels' results are zeroed below).
    const int cl = (cb == 0) ? 0 : cb - 1;
    const int cr = (cb + 4 > WW - 1) ? WW - 1 : cb + 4;

    const float* xb = x + (size_t)n * 3 * HW + (size_t)r * WW;

    float tacc[5][4];
    #pragma unroll
    for (int m = 0; m < 5; ++m)
        #pragma unroll
        for (int j = 0; j < 4; ++j) tacc[m][j] = 0.f;

    #pragma unroll
    for (int i = 0; i < 3; ++i) {
        const float* xr = xb + (size_t)i * HW;

        float4 m4 = *(const float4*)(xr - WW + cb);
        float4 c4 = *(const float4*)(xr + cb);
        float4 p4 = *(const float4*)(xr + WW + cb);

        float rm[6], rc[6], rp[6];
        rm[0] = xr[-WW + cl]; rm[1] = m4.x; rm[2] = m4.y; rm[3] = m4.z; rm[4] = m4.w; rm[5] = xr[-WW + cr];
        rc[0] = xr[cl];       rc[1] = c4.x; rc[2] = c4.y; rc[3] = c4.z; rc[4] = c4.w; rc[5] = xr[cr];
        rp[0] = xr[ WW + cl]; rp[1] = p4.x; rp[2] = p4.y; rp[3] = p4.z; rp[4] = p4.w; rp[5] = xr[ WW + cr];

        float cv[4];
        #pragma unroll
        for (int j = 0; j < 4; ++j) {
            const float ctr = rc[j + 1];
            cv[j] = ctr;
            // _OFFSETS order: (-1,-1),(-1,0),(-1,+1),(0,-1),(+1,-1),(+1,0),(+1,+1),(0,+1)
            float s0 = sgnf(ctr - rm[j]);
            float s1 = sgnf(ctr - rm[j + 1]);
            float s2 = sgnf(ctr - rm[j + 2]);
            float s3 = sgnf(ctr - rc[j]);
            float s4 = sgnf(ctr - rp[j]);
            float s5 = sgnf(ctr - rp[j + 1]);
            float s6 = sgnf(ctr - rp[j + 2]);
            float s7 = sgnf(ctr - rc[j + 2]);

            #pragma unroll
            for (int m = 0; m < 5; ++m) {
                const float* Em = ws + i * 40 + m * 8;  // wave-uniform -> scalar loads
                float a = tacc[m][j];
                a = fmaf(s0, Em[0], a);
                a = fmaf(s1, Em[1], a);
                a = fmaf(s2, Em[2], a);
                a = fmaf(s3, Em[3], a);
                a = fmaf(s4, Em[4], a);
                a = fmaf(s5, Em[5], a);
                a = fmaf(s6, Em[6], a);
                a = fmaf(s7, Em[7], a);
                tacc[m][j] = a;
            }
        }

        // Channels 0..2: center copy, zeroed at col 0 / 255.
        float4 cc;
        cc.x = (cb + 0 != 0 && cb + 0 != WW - 1) ? cv[0] : 0.f;
        cc.y = cv[1];
        cc.z = cv[2];
        cc.w = (cb + 3 != WW - 1) ? cv[3] : 0.f;
        *(float4*)(ob + (size_t)i * HW) = cc;
    }

    // Zero accumulators for border columns so all y channels are 0 there.
    #pragma unroll
    for (int j = 0; j < 4; ++j) {
        const int col = cb + j;
        if (col == 0 || col == WW - 1) {
            #pragma unroll
            for (int m = 0; m < 5; ++m) tacc[m][j] = 0.f;
        }
    }

    // y[o] = sum_m t[m] * wlT[o,m]; 64 dwordx4 stores.
    const float* wlT = ws + 128;
    float* yb = ob + (size_t)3 * HW;
    #pragma unroll
    for (int o = 0; o < 64; ++o) {
        const float* wo = wlT + o * 5;  // wave-uniform, contiguous 5 floats
        const float w0 = wo[0], w1 = wo[1], w2 = wo[2], w3 = wo[3], w4 = wo[4];
        float4 y;
        y.x = fmaf(tacc[4][0], w4, fmaf(tacc[3][0], w3, fmaf(tacc[2][0], w2, fmaf(tacc[1][0], w1, tacc[0][0] * w0))));
        y.y = fmaf(tacc[4][1], w4, fmaf(tacc[3][1], w3, fmaf(tacc[2][1], w2, fmaf(tacc[1][1], w1, tacc[0][1] * w0))));
        y.z = fmaf(tacc[4][2], w4, fmaf(tacc[3][2], w3, fmaf(tacc[2][2], w2, fmaf(tacc[1][2], w1, tacc[0][2] * w0))));
        y.w = fmaf(tacc[4][3], w4, fmaf(tacc[3][3], w3, fmaf(tacc[2][3], w2, fmaf(tacc[1][3], w1, tacc[0][3] * w0))));
        *(float4*)(yb + (size_t)o * HW) = y;
    }
}

extern "C" void kernel_launch(void* const* d_in, const int* in_sizes, int n_in,
                              void* d_out, int out_size, void* d_ws, size_t ws_size,
                              hipStream_t stream) {
    const float* x  = (const float*)d_in[0];
    const float* w  = (const float*)d_in[1];
    const float* wl = (const float*)d_in[2];
    float* out = (float*)d_out;
    float* ws  = (float*)d_ws;

    prep_kernel<<<1, 512, 0, stream>>>(w, wl, ws);
    lbp_kernel<<<32 * 64, 256, 0, stream>>>(x, ws, out);
}